// Round 3
// baseline (904.795 us; speedup 1.0000x reference)
//
#include <hip/hip_runtime.h>

#define N_NODES 100000
#define N_EDGES 3200000
#define F_IN 256
#define CH 16
#define FCN 64
#define NREP 8   // one agg replica per XCD

// ---------------- Kernel A: h = x @ w_gcn   [N,256] x [256,16] -> [N,16]
__global__ __launch_bounds__(256) void k_transform(const float* __restrict__ x,
                                                   const float* __restrict__ w,   // [256][16]
                                                   float* __restrict__ h) {
    __shared__ float wlds[CH][F_IN + 4];   // transposed, padded
    int tid = threadIdx.x;
    for (int i = tid; i < F_IN * CH; i += 256) {
        int k = i >> 4, c = i & 15;
        wlds[c][k] = w[i];
    }
    __syncthreads();
    int c = tid & 15;
    int r = tid >> 4;
    int row = blockIdx.x * 16 + r;
    if (row >= N_NODES) return;
    const float4* xr = reinterpret_cast<const float4*>(x + (size_t)row * F_IN);
    const float4* wr = reinterpret_cast<const float4*>(&wlds[c][0]);
    float acc = 0.f;
    #pragma unroll 8
    for (int k4 = 0; k4 < F_IN / 4; ++k4) {
        float4 xv = xr[k4];
        float4 wv = wr[k4];
        acc = fmaf(xv.x, wv.x, acc);
        acc = fmaf(xv.y, wv.y, acc);
        acc = fmaf(xv.z, wv.z, acc);
        acc = fmaf(xv.w, wv.w, acc);
    }
    h[(size_t)row * CH + c] = acc;
}

// L2-local (no sc0/sc1) f32 atomic add — executes in the issuing XCD's L2.
__device__ __forceinline__ void l2_atomic_add(float* p, float v) {
    asm volatile("global_atomic_add_f32 %0, %1, off" :: "v"(p), "v"(v) : "memory");
}

// ---------------- Kernel B (fast): scatter into per-XCD replica with L2-local atomics.
// 4 lanes per edge; exactly N_EDGES*4 threads (divisible by 256 -> no ragged wave).
__global__ __launch_bounds__(256) void k_scatter_repl(const int* __restrict__ ei,
                                                      const float* __restrict__ ew,
                                                      const float* __restrict__ h,
                                                      float* __restrict__ reps) {  // [NREP][N][CH]
    unsigned xcc;
    asm("s_getreg_b32 %0, hwreg(HW_REG_XCC_ID, 0, 4)" : "=s"(xcc));
    float* agg = reps + (size_t)(xcc & (NREP - 1)) * (N_NODES * CH);

    long long t = (long long)blockIdx.x * 256 + threadIdx.x;
    int e = (int)(t >> 2);
    int g = (int)(t & 3);
    if (e < N_EDGES) {
        int src = ei[e];
        int dst = ei[N_EDGES + e];
        float w = ew[e];
        float4 hv = reinterpret_cast<const float4*>(h)[src * 4 + g];
        float* ap = agg + (size_t)dst * CH + g * 4;
        l2_atomic_add(ap + 0, hv.x * w);
        l2_atomic_add(ap + 1, hv.y * w);
        l2_atomic_add(ap + 2, hv.z * w);
        l2_atomic_add(ap + 3, hv.w * w);
    }
    // asm-issued atomics aren't tracked by the compiler; drain before endpgm.
    asm volatile("s_waitcnt vmcnt(0)");
}

// ---------------- Kernel B (fallback): device-scope atomics straight into agg.
__global__ __launch_bounds__(256) void k_scatter(const int* __restrict__ ei,
                                                 const float* __restrict__ ew,
                                                 const float* __restrict__ h,
                                                 float* __restrict__ agg) {
    long long t = (long long)blockIdx.x * 256 + threadIdx.x;
    int e = (int)(t >> 2);
    int g = (int)(t & 3);
    if (e >= N_EDGES) return;
    int src = ei[e];
    int dst = ei[N_EDGES + e];
    float w = ew[e];
    float4 hv = reinterpret_cast<const float4*>(h)[src * 4 + g];
    float* ap = agg + (size_t)dst * CH + g * 4;
    atomicAdd(ap + 0, hv.x * w);
    atomicAdd(ap + 1, hv.y * w);
    atomicAdd(ap + 2, hv.z * w);
    atomicAdd(ap + 3, hv.w * w);
}

// ---------------- Kernel B2: sum the NREP replicas, apply relu -> agg
__global__ __launch_bounds__(256) void k_reduce(const float* __restrict__ reps,
                                                float* __restrict__ agg) {
    int i = blockIdx.x * 256 + threadIdx.x;            // float4 index
    const int n4 = N_NODES * CH / 4;                   // 400000
    if (i >= n4) return;
    const float4* r4 = reinterpret_cast<const float4*>(reps);
    float4 s = r4[i];
    #pragma unroll
    for (int r = 1; r < NREP; ++r) {
        float4 v = r4[(size_t)r * n4 + i];
        s.x += v.x; s.y += v.y; s.z += v.z; s.w += v.w;
    }
    s.x = fmaxf(s.x, 0.f); s.y = fmaxf(s.y, 0.f);
    s.z = fmaxf(s.z, 0.f); s.w = fmaxf(s.w, 0.f);
    reinterpret_cast<float4*>(agg)[i] = s;
}

// ---------------- Kernel C: per-node head: relu(agg) -> fc(64)+relu -> fc(1)
__global__ __launch_bounds__(256) void k_head(const float* __restrict__ agg,  // [N][16]
                                              const float* __restrict__ w0,   // [16][64]
                                              const float* __restrict__ b0,   // [64]
                                              const float* __restrict__ w1,   // [64]
                                              const float* __restrict__ b1,   // [1]
                                              float* __restrict__ out) {      // [N]
    __shared__ float w0s[CH * FCN];
    __shared__ float w1s[FCN];
    int tid = threadIdx.x;
    for (int i = tid; i < CH * FCN; i += 256) w0s[i] = w0[i];
    if (tid < FCN) w1s[tid] = w1[tid];
    __syncthreads();
    int lane = tid & 63;
    int wv   = tid >> 6;
    int node = blockIdx.x * 4 + wv;
    if (node >= N_NODES) return;
    const float* an = agg + (size_t)node * CH;
    float o1 = b0[lane];
    #pragma unroll
    for (int k = 0; k < CH; ++k) {
        float a = fmaxf(an[k], 0.f);
        o1 = fmaf(a, w0s[k * FCN + lane], o1);
    }
    o1 = fmaxf(o1, 0.f);
    float y = o1 * w1s[lane];
    #pragma unroll
    for (int off = 32; off > 0; off >>= 1) y += __shfl_xor(y, off, 64);
    if (lane == 0) out[node] = y + b1[0];
}

extern "C" void kernel_launch(void* const* d_in, const int* in_sizes, int n_in,
                              void* d_out, int out_size, void* d_ws, size_t ws_size,
                              hipStream_t stream) {
    const float* x  = (const float*)d_in[0];
    const int*   ei = (const int*)  d_in[1];
    const float* ew = (const float*)d_in[2];
    const float* wg = (const float*)d_in[3];
    const float* w0 = (const float*)d_in[4];
    const float* b0 = (const float*)d_in[5];
    const float* w1 = (const float*)d_in[6];
    const float* b1 = (const float*)d_in[7];
    float* out = (float*)d_out;

    const size_t seg = (size_t)N_NODES * CH;           // 1.6M floats
    float* h   = (float*)d_ws;                         // [N][16]
    float* reps = h + seg;                             // [NREP][N][16]
    float* agg  = reps + (size_t)NREP * seg;           // [N][16]
    const size_t need = (2 + NREP) * seg * sizeof(float);  // 64 MB

    k_transform<<<(N_NODES + 15) / 16, 256, 0, stream>>>(x, wg, h);

    long long sc_threads = (long long)N_EDGES * 4;
    int sc_blocks = (int)((sc_threads + 255) / 256);

    if (ws_size >= need) {
        hipMemsetAsync(reps, 0, (size_t)NREP * seg * sizeof(float), stream);
        k_scatter_repl<<<sc_blocks, 256, 0, stream>>>(ei, ew, h, reps);
        k_reduce<<<(N_NODES * CH / 4 + 255) / 256, 256, 0, stream>>>(reps, agg);
    } else {
        float* agg_fb = h + seg;                       // fallback layout: h + agg only
        agg = agg_fb;
        hipMemsetAsync(agg_fb, 0, seg * sizeof(float), stream);
        k_scatter<<<sc_blocks, 256, 0, stream>>>(ei, ew, h, agg_fb);
    }

    k_head<<<(N_NODES + 3) / 4, 256, 0, stream>>>(agg, w0, b0, w1, b1, out);
}

// Round 4
// 719.080 us; speedup vs baseline: 1.2583x; 1.2583x over previous
//
#include <hip/hip_runtime.h>

#define N_NODES 100000
#define N_EDGES 3200000
#define F_IN 256
#define CH 16
#define FCN 64

// ---------------- Kernel A: h = x @ w_gcn   [N,256] x [256,16] -> [N,16]
__global__ __launch_bounds__(256) void k_transform(const float* __restrict__ x,
                                                   const float* __restrict__ w,   // [256][16]
                                                   float* __restrict__ h) {
    __shared__ float wlds[CH][F_IN + 4];   // transposed, padded
    int tid = threadIdx.x;
    for (int i = tid; i < F_IN * CH; i += 256) {
        int k = i >> 4, c = i & 15;
        wlds[c][k] = w[i];
    }
    __syncthreads();
    int c = tid & 15;
    int r = tid >> 4;
    int row = blockIdx.x * 16 + r;
    if (row >= N_NODES) return;
    const float4* xr = reinterpret_cast<const float4*>(x + (size_t)row * F_IN);
    const float4* wr = reinterpret_cast<const float4*>(&wlds[c][0]);
    float acc = 0.f;
    #pragma unroll 8
    for (int k4 = 0; k4 < F_IN / 4; ++k4) {
        float4 xv = xr[k4];
        float4 wv = wr[k4];
        acc = fmaf(xv.x, wv.x, acc);
        acc = fmaf(xv.y, wv.y, acc);
        acc = fmaf(xv.z, wv.z, acc);
        acc = fmaf(xv.w, wv.w, acc);
    }
    h[(size_t)row * CH + c] = acc;
}

// ---------------- CSR build step 1: degree histogram + per-edge rank (3.2M int atomics)
__global__ __launch_bounds__(256) void k_rank(const int* __restrict__ ei,
                                              int* __restrict__ deg,
                                              unsigned short* __restrict__ rank16) {
    int e = blockIdx.x * 256 + threadIdx.x;
    if (e >= N_EDGES) return;
    int dst = ei[N_EDGES + e];
    int r = atomicAdd(&deg[dst], 1);
    rank16[e] = (unsigned short)r;
}

// ---------------- CSR build step 2: exclusive prefix sum of deg -> offs[N+1]
// Single block, 1024 threads, 98 nodes/thread serial + two-level wave scan.
#define SCAN_T 1024
#define PER_T ((N_NODES + SCAN_T - 1) / SCAN_T)   // 98
__global__ __launch_bounds__(1024) void k_scan(const int* __restrict__ deg,
                                               int* __restrict__ offs) {
    __shared__ int wsum[16];
    int t = threadIdx.x;
    int base = t * PER_T;
    int cnt = 0;
    if (base < N_NODES) {
        int end = min(base + PER_T, N_NODES);
        for (int i = base; i < end; ++i) cnt += deg[i];
    }
    int lane = t & 63, w = t >> 6;
    int incl = cnt;
    #pragma unroll
    for (int off = 1; off < 64; off <<= 1) {
        int v = __shfl_up(incl, off, 64);
        if (lane >= off) incl += v;
    }
    if (lane == 63) wsum[w] = incl;
    __syncthreads();
    if (t == 0) {
        int s = 0;
        #pragma unroll
        for (int i = 0; i < 16; ++i) { int v = wsum[i]; wsum[i] = s; s += v; }
    }
    __syncthreads();
    int excl = incl - cnt + wsum[w];
    if (base < N_NODES) {
        int end = min(base + PER_T, N_NODES);
        int run = excl;
        for (int i = base; i < end; ++i) { offs[i] = run; run += deg[i]; }
        if (end == N_NODES) offs[N_NODES] = run;
    }
}

// ---------------- CSR build step 3: deterministic scatter of {src, w} records — NO atomics
__global__ __launch_bounds__(256) void k_scatter_csr(const int* __restrict__ ei,
                                                     const float* __restrict__ ew,
                                                     const unsigned short* __restrict__ rank16,
                                                     const int* __restrict__ offs,
                                                     int2* __restrict__ recs) {
    int e = blockIdx.x * 256 + threadIdx.x;
    if (e >= N_EDGES) return;
    int src = ei[e];
    int dst = ei[N_EDGES + e];
    int pos = offs[dst] + (int)rank16[e];
    int2 r;
    r.x = src;
    r.y = __float_as_int(ew[e]);
    recs[pos] = r;
}

// ---------------- Aggregate: gather-based segment sum, zero atomics.
// 16 lanes per node (one per channel); 16 nodes per 256-thread block.
__global__ __launch_bounds__(256) void k_agg(const int2* __restrict__ recs,
                                             const int* __restrict__ offs,
                                             const float* __restrict__ h,
                                             float* __restrict__ agg) {
    int tid = threadIdx.x;
    int c  = tid & 15;
    int nl = tid >> 4;
    int n = blockIdx.x * 16 + nl;
    if (n >= N_NODES) return;
    int off = offs[n], end = offs[n + 1];
    float acc = 0.f;
    for (int j = off; j < end; ++j) {
        int2 r = recs[j];                               // same addr across 16 lanes: broadcast
        acc = fmaf(h[(size_t)r.x * CH + c], __int_as_float(r.y), acc);  // 16 lanes = one 64B line
    }
    agg[(size_t)n * CH + c] = fmaxf(acc, 0.f);
}

// ---------------- Fallback scatter (device atomics) if ws is too small
__global__ __launch_bounds__(256) void k_scatter_fb(const int* __restrict__ ei,
                                                    const float* __restrict__ ew,
                                                    const float* __restrict__ h,
                                                    float* __restrict__ agg) {
    long long t = (long long)blockIdx.x * 256 + threadIdx.x;
    int e = (int)(t >> 2);
    int g = (int)(t & 3);
    if (e >= N_EDGES) return;
    int src = ei[e];
    int dst = ei[N_EDGES + e];
    float w = ew[e];
    float4 hv = reinterpret_cast<const float4*>(h)[src * 4 + g];
    float* ap = agg + (size_t)dst * CH + g * 4;
    atomicAdd(ap + 0, hv.x * w);
    atomicAdd(ap + 1, hv.y * w);
    atomicAdd(ap + 2, hv.z * w);
    atomicAdd(ap + 3, hv.w * w);
}

// ---------------- Head: relu(agg) -> fc(64)+relu -> fc(1)
__global__ __launch_bounds__(256) void k_head(const float* __restrict__ agg,  // [N][16]
                                              const float* __restrict__ w0,   // [16][64]
                                              const float* __restrict__ b0,   // [64]
                                              const float* __restrict__ w1,   // [64]
                                              const float* __restrict__ b1,   // [1]
                                              float* __restrict__ out) {      // [N]
    __shared__ float w0s[CH * FCN];
    __shared__ float w1s[FCN];
    int tid = threadIdx.x;
    for (int i = tid; i < CH * FCN; i += 256) w0s[i] = w0[i];
    if (tid < FCN) w1s[tid] = w1[tid];
    __syncthreads();
    int lane = tid & 63;
    int wv   = tid >> 6;
    int node = blockIdx.x * 4 + wv;
    if (node >= N_NODES) return;
    const float* an = agg + (size_t)node * CH;
    float o1 = b0[lane];
    #pragma unroll
    for (int k = 0; k < CH; ++k) {
        float a = fmaxf(an[k], 0.f);
        o1 = fmaf(a, w0s[k * FCN + lane], o1);
    }
    o1 = fmaxf(o1, 0.f);
    float y = o1 * w1s[lane];
    #pragma unroll
    for (int off = 32; off > 0; off >>= 1) y += __shfl_xor(y, off, 64);
    if (lane == 0) out[node] = y + b1[0];
}

extern "C" void kernel_launch(void* const* d_in, const int* in_sizes, int n_in,
                              void* d_out, int out_size, void* d_ws, size_t ws_size,
                              hipStream_t stream) {
    const float* x  = (const float*)d_in[0];
    const int*   ei = (const int*)  d_in[1];
    const float* ew = (const float*)d_in[2];
    const float* wg = (const float*)d_in[3];
    const float* w0 = (const float*)d_in[4];
    const float* b0 = (const float*)d_in[5];
    const float* w1 = (const float*)d_in[6];
    const float* b1 = (const float*)d_in[7];
    float* out = (float*)d_out;

    // ---- workspace layout (all 256B-aligned) ----
    char* p = (char*)d_ws;
    float* h = (float*)p;                 p += (size_t)N_NODES * CH * 4;      // 6.4 MB
    int* deg = (int*)p;                   p += 400128;                        // N*4 padded
    int* offs = (int*)p;                  p += 400128;                        // (N+1)*4 padded
    unsigned short* rank16 = (unsigned short*)p; p += (size_t)N_EDGES * 2;    // 6.4 MB
    int2* recs = (int2*)p;                p += (size_t)N_EDGES * 8;           // 25.6 MB
    float* agg = (float*)p;               p += (size_t)N_NODES * CH * 4;      // 6.4 MB
    const size_t need = (size_t)(p - (char*)d_ws);

    k_transform<<<(N_NODES + 15) / 16, 256, 0, stream>>>(x, wg, h);

    const int eblocks = (N_EDGES + 255) / 256;

    if (ws_size >= need) {
        hipMemsetAsync(deg, 0, 400128, stream);
        k_rank<<<eblocks, 256, 0, stream>>>(ei, deg, rank16);
        k_scan<<<1, SCAN_T, 0, stream>>>(deg, offs);
        k_scatter_csr<<<eblocks, 256, 0, stream>>>(ei, ew, rank16, offs, recs);
        k_agg<<<(N_NODES + 15) / 16, 256, 0, stream>>>(recs, offs, h, agg);
    } else {
        float* agg_fb = (float*)((char*)d_ws + (size_t)N_NODES * CH * 4);
        agg = agg_fb;
        hipMemsetAsync(agg_fb, 0, (size_t)N_NODES * CH * 4, stream);
        long long sc_threads = (long long)N_EDGES * 4;
        k_scatter_fb<<<(int)((sc_threads + 255) / 256), 256, 0, stream>>>(ei, ew, h, agg_fb);
    }

    k_head<<<(N_NODES + 3) / 4, 256, 0, stream>>>(agg, w0, b0, w1, b1, out);
}

// Round 5
// 534.583 us; speedup vs baseline: 1.6925x; 1.3451x over previous
//
#include <hip/hip_runtime.h>

#define N_NODES 100000
#define N_EDGES 3200000
#define F_IN 256
#define CH 16
#define FCN 64

#define TBLK ((N_NODES + 15) / 16)      // 6250 transform blocks
#define RBLK ((N_EDGES + 255) / 256)    // 12500 rank blocks
#define SNB 200                         // scan blocks, 512 nodes each

// ---------------- Fused: h = x@w_gcn (blocks < TBLK)  ||  degree+rank (blocks >= TBLK)
__global__ __launch_bounds__(256) void k_transform_rank(
        const float* __restrict__ x, const float* __restrict__ w,   // [256][16]
        float* __restrict__ h,
        const int* __restrict__ ei, int* __restrict__ deg,
        unsigned short* __restrict__ rank16) {
    if (blockIdx.x < TBLK) {
        __shared__ float wlds[CH][F_IN + 4];
        int tid = threadIdx.x;
        for (int i = tid; i < F_IN * CH; i += 256) {
            int k = i >> 4, c = i & 15;
            wlds[c][k] = w[i];
        }
        __syncthreads();
        int c = tid & 15;
        int r = tid >> 4;
        int row = blockIdx.x * 16 + r;
        if (row >= N_NODES) return;
        const float4* xr = reinterpret_cast<const float4*>(x + (size_t)row * F_IN);
        const float4* wr = reinterpret_cast<const float4*>(&wlds[c][0]);
        float acc = 0.f;
        #pragma unroll 8
        for (int k4 = 0; k4 < F_IN / 4; ++k4) {
            float4 xv = xr[k4];
            float4 wv = wr[k4];
            acc = fmaf(xv.x, wv.x, acc);
            acc = fmaf(xv.y, wv.y, acc);
            acc = fmaf(xv.z, wv.z, acc);
            acc = fmaf(xv.w, wv.w, acc);
        }
        h[(size_t)row * CH + c] = acc;
    } else {
        int e = (blockIdx.x - TBLK) * 256 + threadIdx.x;
        if (e >= N_EDGES) return;
        int dst = ei[N_EDGES + e];
        int r = atomicAdd(&deg[dst], 1);
        rank16[e] = (unsigned short)r;
    }
}

// ---------------- Scan pass 1: per-block (512-node) sums -> partials[SNB]
__global__ __launch_bounds__(256) void k_scan1(const int* __restrict__ deg,
                                               int* __restrict__ partials) {
    __shared__ int wsum[4];
    int t = threadIdx.x;
    int idx = blockIdx.x * 512 + 2 * t;
    int s = 0;
    if (idx < N_NODES) {
        int2 d = *reinterpret_cast<const int2*>(deg + idx);   // N even -> idx+1 valid
        s = d.x + d.y;
    }
    #pragma unroll
    for (int off = 32; off > 0; off >>= 1) s += __shfl_xor(s, off, 64);
    if ((t & 63) == 0) wsum[t >> 6] = s;
    __syncthreads();
    if (t == 0) partials[blockIdx.x] = wsum[0] + wsum[1] + wsum[2] + wsum[3];
}

// ---------------- Scan pass 2: exclusive scan of partials -> bases[SNB+1]
__global__ __launch_bounds__(256) void k_scan2(const int* __restrict__ partials,
                                               int* __restrict__ bases) {
    __shared__ int wsum[4];
    int t = threadIdx.x;
    int v = (t < SNB) ? partials[t] : 0;
    int lane = t & 63, w = t >> 6;
    int incl = v;
    #pragma unroll
    for (int off = 1; off < 64; off <<= 1) {
        int u = __shfl_up(incl, off, 64);
        if (lane >= off) incl += u;
    }
    if (lane == 63) wsum[w] = incl;
    __syncthreads();
    if (t == 0) {
        int s = 0;
        #pragma unroll
        for (int i = 0; i < 4; ++i) { int u = wsum[i]; wsum[i] = s; s += u; }
    }
    __syncthreads();
    int excl = incl - v + wsum[w];
    if (t < SNB) {
        bases[t] = excl;
        if (t == SNB - 1) bases[SNB] = excl + v;   // grand total
    }
}

// ---------------- Scan pass 3: local exclusive re-scan + base -> offs[N+1]
__global__ __launch_bounds__(256) void k_scan3(const int* __restrict__ deg,
                                               const int* __restrict__ bases,
                                               int* __restrict__ offs) {
    __shared__ int wsum[4];
    int t = threadIdx.x;
    int idx = blockIdx.x * 512 + 2 * t;
    int2 d = make_int2(0, 0);
    if (idx < N_NODES) d = *reinterpret_cast<const int2*>(deg + idx);
    int s = d.x + d.y;
    int lane = t & 63, w = t >> 6;
    int incl = s;
    #pragma unroll
    for (int off = 1; off < 64; off <<= 1) {
        int u = __shfl_up(incl, off, 64);
        if (lane >= off) incl += u;
    }
    if (lane == 63) wsum[w] = incl;
    __syncthreads();
    if (t == 0) {
        int v0 = wsum[0], v1 = wsum[1], v2 = wsum[2];
        wsum[0] = 0; wsum[1] = v0; wsum[2] = v0 + v1; wsum[3] = v0 + v1 + v2;
    }
    __syncthreads();
    int excl = incl - s + wsum[w] + bases[blockIdx.x];
    if (idx < N_NODES) {
        int2 o;
        o.x = excl;
        o.y = excl + d.x;
        *reinterpret_cast<int2*>(offs + idx) = o;
    }
    if (blockIdx.x == 0 && t == 0) offs[N_NODES] = bases[SNB];
}

// ---------------- Deterministic record scatter — NO atomics
__global__ __launch_bounds__(256) void k_scatter_csr(const int* __restrict__ ei,
                                                     const float* __restrict__ ew,
                                                     const unsigned short* __restrict__ rank16,
                                                     const int* __restrict__ offs,
                                                     int2* __restrict__ recs) {
    int e = blockIdx.x * 256 + threadIdx.x;
    if (e >= N_EDGES) return;
    int src = ei[e];
    int dst = ei[N_EDGES + e];
    int pos = offs[dst] + (int)rank16[e];
    int2 r;
    r.x = src;
    r.y = __float_as_int(ew[e]);
    recs[pos] = r;
}

// ---------------- Fused aggregate + head: one wave per node.
// 64 lanes = 4 record-groups x 16 channels; shfl_xor reduce; in-register FCN head.
__global__ __launch_bounds__(256) void k_agg_head(const int2* __restrict__ recs,
                                                  const int* __restrict__ offs,
                                                  const float* __restrict__ h,
                                                  const float* __restrict__ w0,  // [16][64]
                                                  const float* __restrict__ b0,  // [64]
                                                  const float* __restrict__ w1,  // [64]
                                                  const float* __restrict__ b1,  // [1]
                                                  float* __restrict__ out) {     // [N]
    __shared__ float w0s[CH * FCN];
    __shared__ float w1s[FCN];
    int tid = threadIdx.x;
    for (int i = tid; i < CH * FCN; i += 256) w0s[i] = w0[i];
    if (tid < FCN) w1s[tid] = w1[tid];
    __syncthreads();
    int lane = tid & 63;
    int wv   = tid >> 6;
    int node = blockIdx.x * 4 + wv;
    if (node >= N_NODES) return;
    int c = lane & 15;
    int g = lane >> 4;
    int off = offs[node], end = offs[node + 1];
    float acc = 0.f;
    for (int j = off + g; j < end; j += 4) {
        int2 r = recs[j];                                  // broadcast across 16 lanes
        acc = fmaf(h[(size_t)r.x * CH + c], __int_as_float(r.y), acc);
    }
    acc += __shfl_xor(acc, 16, 64);
    acc += __shfl_xor(acc, 32, 64);
    acc = fmaxf(acc, 0.f);                                 // relu(gcn_out), lane holds channel c
    float o1 = b0[lane];
    #pragma unroll
    for (int k = 0; k < CH; ++k) {
        float a = __shfl(acc, k, 64);                      // lane k holds channel k
        o1 = fmaf(a, w0s[k * FCN + lane], o1);
    }
    o1 = fmaxf(o1, 0.f);
    float y = o1 * w1s[lane];
    #pragma unroll
    for (int off2 = 32; off2 > 0; off2 >>= 1) y += __shfl_xor(y, off2, 64);
    if (lane == 0) out[node] = y + b1[0];
}

// ---------------- Fallback path (ws too small): device atomics + separate head
__global__ __launch_bounds__(256) void k_transform_only(const float* __restrict__ x,
                                                        const float* __restrict__ w,
                                                        float* __restrict__ h) {
    __shared__ float wlds[CH][F_IN + 4];
    int tid = threadIdx.x;
    for (int i = tid; i < F_IN * CH; i += 256) {
        int k = i >> 4, c = i & 15;
        wlds[c][k] = w[i];
    }
    __syncthreads();
    int c = tid & 15;
    int r = tid >> 4;
    int row = blockIdx.x * 16 + r;
    if (row >= N_NODES) return;
    const float4* xr = reinterpret_cast<const float4*>(x + (size_t)row * F_IN);
    const float4* wr = reinterpret_cast<const float4*>(&wlds[c][0]);
    float acc = 0.f;
    for (int k4 = 0; k4 < F_IN / 4; ++k4) {
        float4 xv = xr[k4];
        float4 wv = wr[k4];
        acc = fmaf(xv.x, wv.x, acc);
        acc = fmaf(xv.y, wv.y, acc);
        acc = fmaf(xv.z, wv.z, acc);
        acc = fmaf(xv.w, wv.w, acc);
    }
    h[(size_t)row * CH + c] = acc;
}

__global__ __launch_bounds__(256) void k_scatter_fb(const int* __restrict__ ei,
                                                    const float* __restrict__ ew,
                                                    const float* __restrict__ h,
                                                    float* __restrict__ agg) {
    long long t = (long long)blockIdx.x * 256 + threadIdx.x;
    int e = (int)(t >> 2);
    int g = (int)(t & 3);
    if (e >= N_EDGES) return;
    int src = ei[e];
    int dst = ei[N_EDGES + e];
    float w = ew[e];
    float4 hv = reinterpret_cast<const float4*>(h)[src * 4 + g];
    float* ap = agg + (size_t)dst * CH + g * 4;
    atomicAdd(ap + 0, hv.x * w);
    atomicAdd(ap + 1, hv.y * w);
    atomicAdd(ap + 2, hv.z * w);
    atomicAdd(ap + 3, hv.w * w);
}

__global__ __launch_bounds__(256) void k_head(const float* __restrict__ agg,
                                              const float* __restrict__ w0,
                                              const float* __restrict__ b0,
                                              const float* __restrict__ w1,
                                              const float* __restrict__ b1,
                                              float* __restrict__ out) {
    __shared__ float w0s[CH * FCN];
    __shared__ float w1s[FCN];
    int tid = threadIdx.x;
    for (int i = tid; i < CH * FCN; i += 256) w0s[i] = w0[i];
    if (tid < FCN) w1s[tid] = w1[tid];
    __syncthreads();
    int lane = tid & 63;
    int wv   = tid >> 6;
    int node = blockIdx.x * 4 + wv;
    if (node >= N_NODES) return;
    const float* an = agg + (size_t)node * CH;
    float o1 = b0[lane];
    #pragma unroll
    for (int k = 0; k < CH; ++k) {
        float a = fmaxf(an[k], 0.f);
        o1 = fmaf(a, w0s[k * FCN + lane], o1);
    }
    o1 = fmaxf(o1, 0.f);
    float y = o1 * w1s[lane];
    #pragma unroll
    for (int off = 32; off > 0; off >>= 1) y += __shfl_xor(y, off, 64);
    if (lane == 0) out[node] = y + b1[0];
}

extern "C" void kernel_launch(void* const* d_in, const int* in_sizes, int n_in,
                              void* d_out, int out_size, void* d_ws, size_t ws_size,
                              hipStream_t stream) {
    const float* x  = (const float*)d_in[0];
    const int*   ei = (const int*)  d_in[1];
    const float* ew = (const float*)d_in[2];
    const float* wg = (const float*)d_in[3];
    const float* w0 = (const float*)d_in[4];
    const float* b0 = (const float*)d_in[5];
    const float* w1 = (const float*)d_in[6];
    const float* b1 = (const float*)d_in[7];
    float* out = (float*)d_out;

    // ---- workspace layout ----
    char* p = (char*)d_ws;
    float* h = (float*)p;                        p += (size_t)N_NODES * CH * 4;   // 6.4 MB
    int* deg = (int*)p;                          p += 400128;                     // N*4 padded
    int* offs = (int*)p;                         p += 400640;                     // (N+1)*4 padded
    int* partials = (int*)p;                     p += 1024;                       // SNB ints
    int* bases = (int*)p;                        p += 1024;                       // SNB+1 ints
    unsigned short* rank16 = (unsigned short*)p; p += (size_t)N_EDGES * 2;        // 6.4 MB
    int2* recs = (int2*)p;                       p += (size_t)N_EDGES * 8;        // 25.6 MB
    const size_t need = (size_t)(p - (char*)d_ws);

    const int eblocks = (N_EDGES + 255) / 256;

    if (ws_size >= need) {
        hipMemsetAsync(deg, 0, 400128, stream);
        k_transform_rank<<<TBLK + RBLK, 256, 0, stream>>>(x, wg, h, ei, deg, rank16);
        k_scan1<<<SNB, 256, 0, stream>>>(deg, partials);
        k_scan2<<<1, 256, 0, stream>>>(partials, bases);
        k_scan3<<<SNB, 256, 0, stream>>>(deg, bases, offs);
        k_scatter_csr<<<eblocks, 256, 0, stream>>>(ei, ew, rank16, offs, recs);
        k_agg_head<<<(N_NODES + 3) / 4, 256, 0, stream>>>(recs, offs, h, w0, b0, w1, b1, out);
    } else {
        float* agg = (float*)((char*)d_ws + (size_t)N_NODES * CH * 4);
        hipMemsetAsync(agg, 0, (size_t)N_NODES * CH * 4, stream);
        k_transform_only<<<TBLK, 256, 0, stream>>>(x, wg, h);
        long long sc_threads = (long long)N_EDGES * 4;
        k_scatter_fb<<<(int)((sc_threads + 255) / 256), 256, 0, stream>>>(ei, ew, h, agg);
        k_head<<<(N_NODES + 3) / 4, 256, 0, stream>>>(agg, w0, b0, w1, b1, out);
    }
}